// Round 4
// baseline (489.035 us; speedup 1.0000x reference)
//
#include <hip/hip_runtime.h>
#include <cstdint>
#include <cstddef>

#define NHEADS 16
#define DHEAD 64
#define BATCH 4
#define SEQ 2048
// M = 8192, D = 1024

typedef __attribute__((ext_vector_type(8))) __bf16 bf16x8;
typedef __attribute__((ext_vector_type(4))) float f32x4;

__device__ __forceinline__ unsigned short f2bf(float f) {
  union { float f; unsigned u; } v; v.f = f;
  unsigned r = v.u + 0x7FFFu + ((v.u >> 16) & 1u);  // RNE
  return (unsigned short)(r >> 16);
}

__device__ __forceinline__ ushort4 cvt4(float4 f) {
  ushort4 o;
  o.x = f2bf(f.x); o.y = f2bf(f.y); o.z = f2bf(f.z); o.w = f2bf(f.w);
  return o;
}

// ---------------- QKV GEMM: f32 x [8192,1024] @ f32 w_qkv [3072,1024]^T + bias ----------------
// 128x128 tile, BK=32, 4 waves (2x2), each wave 64x64 = 4x4 MFMA 16x16x32 tiles.
// f32 inputs converted to bf16 in registers during LDS staging.
// Epilogue: Q (pre-scaled 1/8), K -> [bh][seq][64] bf16; V -> [bh][64][seq] bf16 (transposed).
__global__ __launch_bounds__(256) void gemm_qkv(
    const float* __restrict__ A,             // x f32 [8192][1024]
    const float* __restrict__ Bw,            // w_qkv f32 [3072][1024]
    const float* __restrict__ bias,          // [3072]
    unsigned short* __restrict__ qb,         // [64][2048][64]
    unsigned short* __restrict__ kb,         // [64][2048][64]
    unsigned short* __restrict__ vt) {       // [64][64][2048]  (V^T)
  __shared__ unsigned short As[128 * 32];
  __shared__ unsigned short Bs[128 * 32];
  const int t = threadIdx.x;
  const int lane = t & 63;
  const int wv = t >> 6;
  const int wm = wv >> 1, wn = wv & 1;
  const int quad = lane >> 4, l15 = lane & 15;
  const int bM = blockIdx.y * 128;
  const int bN = blockIdx.x * 128;
  const int r0 = t >> 2;        // 0..63
  const int c0 = (t & 3) * 8;   // 0,8,16,24

  f32x4 acc[4][4];
#pragma unroll
  for (int i = 0; i < 4; i++)
#pragma unroll
    for (int j = 0; j < 4; j++) acc[i][j] = f32x4{0.f, 0.f, 0.f, 0.f};

  const size_t aR0 = (size_t)(bM + r0) * 1024 + c0;
  const size_t aR1 = (size_t)(bM + 64 + r0) * 1024 + c0;
  const size_t bR0 = (size_t)(bN + r0) * 1024 + c0;
  const size_t bR1 = (size_t)(bN + 64 + r0) * 1024 + c0;

  for (int kt = 0; kt < 32; ++kt) {
    const int k0 = kt * 32;
    float4 a00 = *(const float4*)&A[aR0 + k0];
    float4 a01 = *(const float4*)&A[aR0 + k0 + 4];
    float4 a10 = *(const float4*)&A[aR1 + k0];
    float4 a11 = *(const float4*)&A[aR1 + k0 + 4];
    float4 b00 = *(const float4*)&Bw[bR0 + k0];
    float4 b01 = *(const float4*)&Bw[bR0 + k0 + 4];
    float4 b10 = *(const float4*)&Bw[bR1 + k0];
    float4 b11 = *(const float4*)&Bw[bR1 + k0 + 4];
    __syncthreads();
    *(ushort4*)&As[r0 * 32 + c0] = cvt4(a00);
    *(ushort4*)&As[r0 * 32 + c0 + 4] = cvt4(a01);
    *(ushort4*)&As[(64 + r0) * 32 + c0] = cvt4(a10);
    *(ushort4*)&As[(64 + r0) * 32 + c0 + 4] = cvt4(a11);
    *(ushort4*)&Bs[r0 * 32 + c0] = cvt4(b00);
    *(ushort4*)&Bs[r0 * 32 + c0 + 4] = cvt4(b01);
    *(ushort4*)&Bs[(64 + r0) * 32 + c0] = cvt4(b10);
    *(ushort4*)&Bs[(64 + r0) * 32 + c0 + 4] = cvt4(b11);
    __syncthreads();

    bf16x8 af[4], bf[4];
#pragma unroll
    for (int mi = 0; mi < 4; mi++)
      af[mi] = *(const bf16x8*)&As[(wm * 64 + mi * 16 + l15) * 32 + quad * 8];
#pragma unroll
    for (int ni = 0; ni < 4; ni++)
      bf[ni] = *(const bf16x8*)&Bs[(wn * 64 + ni * 16 + l15) * 32 + quad * 8];
#pragma unroll
    for (int mi = 0; mi < 4; mi++)
#pragma unroll
      for (int ni = 0; ni < 4; ni++)
        acc[mi][ni] = __builtin_amdgcn_mfma_f32_16x16x32_bf16(af[mi], bf[ni], acc[mi][ni], 0, 0, 0);
  }

  // epilogue: C row = bM+wm*64+mi*16+quad*4+reg, col = bN+wn*64+ni*16+l15
#pragma unroll
  for (int mi = 0; mi < 4; mi++) {
#pragma unroll
    for (int ni = 0; ni < 4; ni++) {
      const int n_col = bN + wn * 64 + ni * 16 + l15;
      const int m0 = bM + wm * 64 + mi * 16 + quad * 4;  // multiple of 4; all 4 rows same batch
      const float bv = bias[n_col];
      const int s = n_col >> 10;          // wave-uniform (16-col groups aligned)
      const int rem = n_col & 1023;
      const int h = rem >> 6, d = rem & 63;
      const int b = m0 >> 11;
      const int nn = m0 & 2047;
      const int bh = b * 16 + h;
      if (s == 2) {
        // V transposed: 4 consecutive seq positions -> contiguous ushort4
        ushort4 o;
        o.x = f2bf(acc[mi][ni][0] + bv);
        o.y = f2bf(acc[mi][ni][1] + bv);
        o.z = f2bf(acc[mi][ni][2] + bv);
        o.w = f2bf(acc[mi][ni][3] + bv);
        *(ushort4*)&vt[((size_t)bh * 64 + d) * 2048 + nn] = o;
      } else {
        unsigned short* dst = (s == 0) ? qb : kb;
        const float scale = (s == 0) ? 0.125f : 1.0f;
#pragma unroll
        for (int r = 0; r < 4; r++) {
          float v = (acc[mi][ni][r] + bv) * scale;
          dst[((size_t)bh * 2048 + nn + r) * 64 + d] = f2bf(v);
        }
      }
    }
  }
}

// ---------------- Flash attention: per (bh, 64 q-rows) block ----------------
__global__ __launch_bounds__(256) void attn(const unsigned short* __restrict__ qb,
                                            const unsigned short* __restrict__ kb,
                                            const unsigned short* __restrict__ vt,
                                            unsigned short* __restrict__ ob) {
  __shared__ unsigned short Qs[64 * 80];
  __shared__ unsigned short Ks[64 * 80];
  __shared__ unsigned short Vs[64 * 80];   // V^T tile: [d][key], stride 80
  __shared__ unsigned short Ps[4][16 * 72];
  const int bh = blockIdx.y;
  const int q0 = blockIdx.x * 64;
  const int t = threadIdx.x, lane = t & 63, wv = t >> 6;
  const int quad = lane >> 4, l15 = lane & 15;
  const int rr = t >> 3, c8 = (t & 7) * 8;

#pragma unroll
  for (int i = 0; i < 2; i++) {
    int r = i * 32 + rr;
    uint4 v = *(const uint4*)&qb[((size_t)bh * 2048 + q0 + r) * 64 + c8];
    *(uint4*)&Qs[r * 80 + c8] = v;
  }
  __syncthreads();
  bf16x8 qf0 = *(const bf16x8*)&Qs[(wv * 16 + l15) * 80 + quad * 8];
  bf16x8 qf1 = *(const bf16x8*)&Qs[(wv * 16 + l15) * 80 + 32 + quad * 8];

  f32x4 acco[4];
#pragma unroll
  for (int i = 0; i < 4; i++) acco[i] = f32x4{0.f, 0.f, 0.f, 0.f};
  float mi_[4] = {-3e38f, -3e38f, -3e38f, -3e38f};
  float li_[4] = {0.f, 0.f, 0.f, 0.f};

  for (int kt = 0; kt < 32; ++kt) {
    __syncthreads();
#pragma unroll
    for (int i = 0; i < 2; i++) {
      int r = i * 32 + rr;
      uint4 kv = *(const uint4*)&kb[((size_t)bh * 2048 + kt * 64 + r) * 64 + c8];
      *(uint4*)&Ks[r * 80 + c8] = kv;
      uint4 vv = *(const uint4*)&vt[((size_t)bh * 64 + r) * 2048 + kt * 64 + c8];
      *(uint4*)&Vs[r * 80 + c8] = vv;
    }
    __syncthreads();

    // S = Q K^T (scale folded into Q). C layout: row(q)=quad*4+reg, col(key)=ct*16+l15
    f32x4 s[4];
#pragma unroll
    for (int ct = 0; ct < 4; ct++) {
      bf16x8 kf0 = *(const bf16x8*)&Ks[(ct * 16 + l15) * 80 + quad * 8];
      bf16x8 kf1 = *(const bf16x8*)&Ks[(ct * 16 + l15) * 80 + 32 + quad * 8];
      f32x4 z = f32x4{0.f, 0.f, 0.f, 0.f};
      z = __builtin_amdgcn_mfma_f32_16x16x32_bf16(qf0, kf0, z, 0, 0, 0);
      s[ct] = __builtin_amdgcn_mfma_f32_16x16x32_bf16(qf1, kf1, z, 0, 0, 0);
    }

    // online softmax over 64 keys
    float mt[4];
#pragma unroll
    for (int r = 0; r < 4; r++)
      mt[r] = fmaxf(fmaxf(s[0][r], s[1][r]), fmaxf(s[2][r], s[3][r]));
#pragma unroll
    for (int off = 1; off < 16; off <<= 1)
#pragma unroll
      for (int r = 0; r < 4; r++) mt[r] = fmaxf(mt[r], __shfl_xor(mt[r], off));

    float alpha[4];
#pragma unroll
    for (int r = 0; r < 4; r++) {
      float mn = fmaxf(mi_[r], mt[r]);
      alpha[r] = __expf(mi_[r] - mn);
      mi_[r] = mn;
    }
    float p[4][4];
    float lt[4] = {0.f, 0.f, 0.f, 0.f};
#pragma unroll
    for (int ct = 0; ct < 4; ct++)
#pragma unroll
      for (int r = 0; r < 4; r++) {
        p[ct][r] = __expf(s[ct][r] - mi_[r]);
        lt[r] += p[ct][r];
      }
#pragma unroll
    for (int off = 1; off < 16; off <<= 1)
#pragma unroll
      for (int r = 0; r < 4; r++) lt[r] += __shfl_xor(lt[r], off);
#pragma unroll
    for (int r = 0; r < 4; r++) li_[r] = li_[r] * alpha[r] + lt[r];
#pragma unroll
    for (int ni = 0; ni < 4; ni++)
#pragma unroll
      for (int r = 0; r < 4; r++) acco[ni][r] *= alpha[r];

    // P: C-layout -> A-layout via per-wave LDS round trip (stride 72 elems = 144B)
#pragma unroll
    for (int ct = 0; ct < 4; ct++)
#pragma unroll
      for (int r = 0; r < 4; r++)
        Ps[wv][(quad * 4 + r) * 72 + ct * 16 + l15] = f2bf(p[ct][r]);

    bf16x8 pf0 = *(const bf16x8*)&Ps[wv][l15 * 72 + quad * 8];
    bf16x8 pf1 = *(const bf16x8*)&Ps[wv][l15 * 72 + 32 + quad * 8];
#pragma unroll
    for (int ni = 0; ni < 4; ni++) {
      bf16x8 vf0 = *(const bf16x8*)&Vs[(ni * 16 + l15) * 80 + quad * 8];
      bf16x8 vf1 = *(const bf16x8*)&Vs[(ni * 16 + l15) * 80 + 32 + quad * 8];
      acco[ni] = __builtin_amdgcn_mfma_f32_16x16x32_bf16(pf0, vf0, acco[ni], 0, 0, 0);
      acco[ni] = __builtin_amdgcn_mfma_f32_16x16x32_bf16(pf1, vf1, acco[ni], 0, 0, 0);
    }
  }

  const int b = bh >> 4, h = bh & 15;
  float inv[4];
#pragma unroll
  for (int r = 0; r < 4; r++) inv[r] = 1.0f / li_[r];
#pragma unroll
  for (int ni = 0; ni < 4; ni++)
#pragma unroll
    for (int r = 0; r < 4; r++) {
      size_t row = (size_t)b * 2048 + q0 + wv * 16 + quad * 4 + r;
      ob[row * 1024 + h * 64 + ni * 16 + l15] = f2bf(acco[ni][r] * inv[r]);
    }
}

// ---------------- Output GEMM: bf16 ob [8192,1024] @ f32 w_out [1024,1024]^T + bias -> fp32 ----------------
__global__ __launch_bounds__(256) void gemm_out(
    const unsigned short* __restrict__ A,    // attn out bf16 [8192][1024]
    const float* __restrict__ Bw,            // w_out f32 [1024][1024]
    const float* __restrict__ bias,          // [1024]
    float* __restrict__ out) {
  __shared__ unsigned short As[128 * 32];
  __shared__ unsigned short Bs[128 * 32];
  const int t = threadIdx.x;
  const int lane = t & 63;
  const int wv = t >> 6;
  const int wm = wv >> 1, wn = wv & 1;
  const int quad = lane >> 4, l15 = lane & 15;
  const int bM = blockIdx.y * 128;
  const int bN = blockIdx.x * 128;
  const int r0 = t >> 2;
  const int c0 = (t & 3) * 8;

  f32x4 acc[4][4];
#pragma unroll
  for (int i = 0; i < 4; i++)
#pragma unroll
    for (int j = 0; j < 4; j++) acc[i][j] = f32x4{0.f, 0.f, 0.f, 0.f};

  const size_t aR0 = (size_t)(bM + r0) * 1024 + c0;
  const size_t aR1 = (size_t)(bM + 64 + r0) * 1024 + c0;
  const size_t bR0 = (size_t)(bN + r0) * 1024 + c0;
  const size_t bR1 = (size_t)(bN + 64 + r0) * 1024 + c0;

  for (int kt = 0; kt < 32; ++kt) {
    const int k0 = kt * 32;
    uint4 a0 = *(const uint4*)&A[aR0 + k0];
    uint4 a1 = *(const uint4*)&A[aR1 + k0];
    float4 b00 = *(const float4*)&Bw[bR0 + k0];
    float4 b01 = *(const float4*)&Bw[bR0 + k0 + 4];
    float4 b10 = *(const float4*)&Bw[bR1 + k0];
    float4 b11 = *(const float4*)&Bw[bR1 + k0 + 4];
    __syncthreads();
    *(uint4*)&As[r0 * 32 + c0] = a0;
    *(uint4*)&As[(64 + r0) * 32 + c0] = a1;
    *(ushort4*)&Bs[r0 * 32 + c0] = cvt4(b00);
    *(ushort4*)&Bs[r0 * 32 + c0 + 4] = cvt4(b01);
    *(ushort4*)&Bs[(64 + r0) * 32 + c0] = cvt4(b10);
    *(ushort4*)&Bs[(64 + r0) * 32 + c0 + 4] = cvt4(b11);
    __syncthreads();

    bf16x8 af[4], bf[4];
#pragma unroll
    for (int mi = 0; mi < 4; mi++)
      af[mi] = *(const bf16x8*)&As[(wm * 64 + mi * 16 + l15) * 32 + quad * 8];
#pragma unroll
    for (int ni = 0; ni < 4; ni++)
      bf[ni] = *(const bf16x8*)&Bs[(wn * 64 + ni * 16 + l15) * 32 + quad * 8];
#pragma unroll
    for (int mi = 0; mi < 4; mi++)
#pragma unroll
      for (int ni = 0; ni < 4; ni++)
        acc[mi][ni] = __builtin_amdgcn_mfma_f32_16x16x32_bf16(af[mi], bf[ni], acc[mi][ni], 0, 0, 0);
  }

#pragma unroll
  for (int mi = 0; mi < 4; mi++) {
#pragma unroll
    for (int ni = 0; ni < 4; ni++) {
      const int n_col = bN + wn * 64 + ni * 16 + l15;
      const int m0 = bM + wm * 64 + mi * 16 + quad * 4;
      const float bv = bias[n_col];
#pragma unroll
      for (int r = 0; r < 4; r++)
        out[(size_t)(m0 + r) * 1024 + n_col] = acc[mi][ni][r] + bv;
    }
  }
}

extern "C" void kernel_launch(void* const* d_in, const int* in_sizes, int n_in,
                              void* d_out, int out_size, void* d_ws, size_t ws_size,
                              hipStream_t stream) {
  const float* x = (const float*)d_in[0];
  const float* w_qkv = (const float*)d_in[1];
  const float* b_qkv = (const float*)d_in[2];
  const float* w_out = (const float*)d_in[3];
  const float* b_out = (const float*)d_in[4];
  float* out = (float*)d_out;
  char* ws = (char*)d_ws;

  // ---- workspace layout: 32 MiB total ----
  // [0,16MiB)   vt : V^T [64][64][2048] bf16
  // [16,32MiB)  ob : attention output bf16 [8192][1024]
  unsigned short* vt = (unsigned short*)(ws);
  unsigned short* ob = (unsigned short*)(ws + (size_t)16 * 1024 * 1024);

  // ---- qb/kb live inside d_out (32 MiB): lifetime ends before gemm_out writes it ----
  unsigned short* qb = (unsigned short*)d_out;                 // 16 MiB
  unsigned short* kb = qb + (size_t)8 * 1024 * 1024;           // 16 MiB

  gemm_qkv<<<dim3(24, 64), 256, 0, stream>>>(x, w_qkv, b_qkv, qb, kb, vt);
  attn<<<dim3(32, 64), 256, 0, stream>>>(qb, kb, vt, ob);
  gemm_out<<<dim3(8, 64), 256, 0, stream>>>(ob, w_out, b_out, out);
}